// Round 2
// baseline (14534.294 us; speedup 1.0000x reference)
//
#include <hip/hip_runtime.h>
#include <hip/hip_bf16.h>
#include <math.h>

// Model constants
#define PP 32      // patch
#define OO 128     // outputs per patch
#define QQ 10      // quantiles
#define MM 4       // AR patches per step
#define LL 8       // layers
#define HH 16      // heads
#define HD 64      // head dim
#define DD 1024    // D = H*HD
#define DFF 4096
#define NPATCH 16  // context patches (512/32)
#define B2 64      // 32 batches x {+x, -x}
#define CMAX 20    // max cache length
#define EPSF 1e-6f

// ---------------------------------------------------------------------------
// Running stats (Chan update), context: 16 patches from scratch. Also is_pos.
__global__ void stats_ctx_kernel(const float* __restrict__ x, float* __restrict__ ctx_mu,
                                 float* __restrict__ ctx_sg, float* __restrict__ ispos,
                                 float* __restrict__ normed)
{
    int b2 = blockIdx.x;            // 0..63
    int tid = threadIdx.x;          // 64
    float sign = (b2 < 32) ? 1.f : -1.f;
    const float* xp = x + (size_t)(b2 & 31) * 512;
    __shared__ float smu[NPATCH], ssg[NPATCH];
    if (tid == 0) {
        float n = 0.f, mu = 0.f, sg = 0.f;
        for (int t = 0; t < NPATCH; t++) {
            float s1 = 0.f;
            for (int p = 0; p < PP; p++) s1 += sign * xp[t * PP + p];
            float nn2 = n + 32.f;
            float nmu_ = (n * mu + s1) / nn2;
            float m2 = n * sg * sg;
            for (int p = 0; p < PP; p++) {
                float xv = sign * xp[t * PP + p];
                m2 += (xv - mu) * (xv - nmu_);
            }
            sg = sqrtf(fmaxf(m2 / nn2, 1e-12f));
            mu = nmu_; n = nn2;
            smu[t] = mu; ssg[t] = sg;
            ctx_mu[b2 * NPATCH + t] = mu;
            ctx_sg[b2 * NPATCH + t] = sg;
        }
        if (b2 < 32) {
            int ok = 1;
            for (int i = 0; i < 512; i++) if (xp[i] < 0.f) ok = 0;
            ispos[b2] = (float)ok;
        }
    }
    __syncthreads();
    for (int i = tid; i < 512; i += 64) {
        int t = i >> 5;
        normed[(size_t)b2 * 512 + i] = (sign * xp[i] - smu[t]) / (ssg[t] + EPSF);
    }
}

// AR stats: continue from n=512 state with 4 new patches (= last 128 preds).
__global__ void stats_ar_kernel(const float* __restrict__ lastc, const float* __restrict__ ctx_mu,
                                const float* __restrict__ ctx_sg, float* __restrict__ nmu,
                                float* __restrict__ nsg, float* __restrict__ normed)
{
    int b2 = blockIdx.x;
    int tid = threadIdx.x;
    __shared__ float smu[MM], ssg[MM];
    const float* xp = lastc + (size_t)b2 * 128;
    if (tid == 0) {
        float n = 512.f;
        float mu = ctx_mu[b2 * NPATCH + 15];
        float sg = ctx_sg[b2 * NPATCH + 15];
        for (int t = 0; t < MM; t++) {
            float s1 = 0.f;
            for (int p = 0; p < PP; p++) s1 += xp[t * PP + p];
            float nn2 = n + 32.f;
            float nmu_ = (n * mu + s1) / nn2;
            float m2 = n * sg * sg;
            for (int p = 0; p < PP; p++) {
                float xv = xp[t * PP + p];
                m2 += (xv - mu) * (xv - nmu_);
            }
            sg = sqrtf(fmaxf(m2 / nn2, 1e-12f));
            mu = nmu_; n = nn2;
            smu[t] = mu; ssg[t] = sg;
            nmu[b2 * MM + t] = mu;
            nsg[b2 * MM + t] = sg;
        }
    }
    __syncthreads();
    for (int i = tid; i < 128; i += 64) {
        int t = i >> 5;
        normed[(size_t)b2 * 128 + i] = (xp[i] - smu[t]) / (ssg[t] + EPSF);
    }
}

// ---------------------------------------------------------------------------
// Embedding: hdd[row, :] = normed[row, 0:32] @ W_in[0:32, :] + b_in
// (mask half of feat is all zeros -> W_in rows 32..63 contribute nothing)
__global__ __launch_bounds__(256) void embed_kernel(const float* __restrict__ normed,
                                                    const float* __restrict__ Win,
                                                    const float* __restrict__ bin,
                                                    float* __restrict__ hdd)
{
    int row = blockIdx.x;
    int tid = threadIdx.x;
    __shared__ float p[PP];
    if (tid < PP) p[tid] = normed[(size_t)row * PP + tid];
    __syncthreads();
    for (int c = tid; c < DD; c += 256) {
        float s = bin[c];
        for (int k = 0; k < PP; k++) s = fmaf(p[k], Win[k * DD + c], s);
        hdd[(size_t)row * DD + c] = s;
    }
}

// ---------------------------------------------------------------------------
// LayerNorm: out = (x - mean) * rsqrt(var + EPS) * scale
__global__ __launch_bounds__(256) void layernorm_kernel(const float* __restrict__ in,
                                                        float* __restrict__ out,
                                                        const float* __restrict__ scale, int D)
{
    int row = blockIdx.x;
    int tid = threadIdx.x;
    const float* x = in + (size_t)row * D;
    float* o = out + (size_t)row * D;
    __shared__ float red[256];
    float s = 0.f;
    for (int i = tid; i < D; i += 256) s += x[i];
    red[tid] = s; __syncthreads();
    for (int st = 128; st > 0; st >>= 1) { if (tid < st) red[tid] += red[tid + st]; __syncthreads(); }
    float m = red[0] / (float)D;
    __syncthreads();
    float v = 0.f;
    for (int i = tid; i < D; i += 256) { float d = x[i] - m; v += d * d; }
    red[tid] = v; __syncthreads();
    for (int st = 128; st > 0; st >>= 1) { if (tid < st) red[tid] += red[tid + st]; __syncthreads(); }
    float inv = rsqrtf(red[0] / (float)D + EPSF);
    for (int i = tid; i < D; i += 256) o[i] = (x[i] - m) * inv * scale[i];
}

// ---------------------------------------------------------------------------
// GEMM: C[M,N] = A[M,K] @ B[K,N]; epilogue 0=none, 1=gelu(tanh), 2=residual add
__device__ inline float gelu_tanh(float x)
{
    float x3 = x * x * x;
    float t = tanhf(0.7978845608028654f * (x + 0.044715f * x3));
    return 0.5f * x * (1.f + t);
}

__global__ __launch_bounds__(256) void sgemm_kernel(const float* __restrict__ A,
                                                    const float* __restrict__ B,
                                                    float* __restrict__ C,
                                                    int M, int N, int K, int epilogue)
{
    __shared__ float As[16][65];
    __shared__ float Bs[16][65];
    int tid = threadIdx.x;
    int tn = tid & 15, tm = tid >> 4;
    int row0 = blockIdx.y * 64, col0 = blockIdx.x * 64;
    float acc[4][4] = {};
    for (int k0 = 0; k0 < K; k0 += 16) {
        #pragma unroll
        for (int i = 0; i < 4; i++) {
            int e = tid + i * 256;
            int r = e >> 4, c = e & 15;
            As[c][r] = A[(size_t)(row0 + r) * K + k0 + c];
        }
        #pragma unroll
        for (int i = 0; i < 4; i++) {
            int e = tid + i * 256;
            int r = e >> 6, c = e & 63;
            Bs[r][c] = B[(size_t)(k0 + r) * N + col0 + c];
        }
        __syncthreads();
        #pragma unroll
        for (int kk = 0; kk < 16; kk++) {
            float a[4], b[4];
            #pragma unroll
            for (int i = 0; i < 4; i++) a[i] = As[kk][tm * 4 + i];
            #pragma unroll
            for (int j = 0; j < 4; j++) b[j] = Bs[kk][tn * 4 + j];
            #pragma unroll
            for (int i = 0; i < 4; i++)
                #pragma unroll
                for (int j = 0; j < 4; j++) acc[i][j] = fmaf(a[i], b[j], acc[i][j]);
        }
        __syncthreads();
    }
    for (int i = 0; i < 4; i++) {
        int r = row0 + tm * 4 + i;
        for (int j = 0; j < 4; j++) {
            int c = col0 + tn * 4 + j;
            float v = acc[i][j];
            if (epilogue == 1) v = gelu_tanh(v);
            else if (epilogue == 2) v += C[(size_t)r * N + c];
            C[(size_t)r * N + c] = v;
        }
    }
}

// ---------------------------------------------------------------------------
// Scatter K,V from qkv buffer into per-layer caches (b, h, CMAX, HD)
__global__ void scatter_kv_kernel(const float* __restrict__ qkv, float* __restrict__ Kc,
                                  float* __restrict__ Vc, int Nn, int off)
{
    int idx = blockIdx.x * 256 + threadIdx.x;   // rows * 1024 total
    int row = idx >> 10, col = idx & 1023;
    int b = row / Nn, n = row % Nn;
    int h = col >> 6, hd = col & 63;
    size_t dst = (((size_t)(b * HH + h) * CMAX) + off + n) * HD + hd;
    Kc[dst] = qkv[(size_t)row * 3072 + 1024 + col];
    Vc[dst] = qkv[(size_t)row * 3072 + 2048 + col];
}

// ---------------------------------------------------------------------------
// Attention: one wave per (b, h, n). Causal over len = n + off + 1 cache rows.
__global__ __launch_bounds__(64) void attn_kernel(const float* __restrict__ qkv,
                                                  const float* __restrict__ Kc,
                                                  const float* __restrict__ Vc,
                                                  float* __restrict__ outb, int Nn, int off)
{
    int gid = blockIdx.x;
    int n = gid % Nn;
    int h = (gid / Nn) & (HH - 1);
    int b = gid / (Nn * HH);
    int lane = threadIdx.x;
    int len = n + off + 1;
    const float* q = qkv + ((size_t)(b * Nn + n)) * 3072 + h * HD;
    const float* Kb = Kc + ((size_t)(b * HH + h)) * CMAX * HD;
    const float* Vb = Vc + ((size_t)(b * HH + h)) * CMAX * HD;

    float score = -1e30f;
    if (lane < len) {
        const float* kr = Kb + lane * HD;
        float s = 0.f;
        for (int d = 0; d < HD; d++) s = fmaf(q[d], kr[d], s);
        score = s * 0.125f;   // 1/sqrt(64)
    }
    float mx = score;
    for (int o = 32; o > 0; o >>= 1) mx = fmaxf(mx, __shfl_xor(mx, o, 64));
    float e = (lane < len) ? expf(score - mx) : 0.f;
    float sm = e;
    for (int o = 32; o > 0; o >>= 1) sm += __shfl_xor(sm, o, 64);
    float att = e / sm;
    __shared__ float satt[64];
    satt[lane] = att;
    __syncthreads();
    float acc = 0.f;
    for (int m = 0; m < len; m++) acc = fmaf(satt[m], Vb[m * HD + lane], acc);
    outb[((size_t)(b * Nn + n)) * DD + h * HD + lane] = acc;
}

// ---------------------------------------------------------------------------
// Final head: only quantile-5 columns of Wout; + revin. One block per b2.
__global__ __launch_bounds__(128) void out5_kernel(const float* __restrict__ xn,
                                                   const float* __restrict__ Wout,
                                                   const float* __restrict__ mus,
                                                   const float* __restrict__ sgs,
                                                   float* __restrict__ last, int Nn)
{
    int b2 = blockIdx.x;
    int o = threadIdx.x;          // 0..127
    int row = b2 * Nn + (Nn - 1);
    const float* xr = xn + (size_t)row * DD;
    const float* w = Wout + o * QQ + 5;
    float s = 0.f;
    for (int k = 0; k < DD; k++) s = fmaf(xr[k], w[(size_t)k * (OO * QQ)], s);
    float mu = mus[b2 * Nn + (Nn - 1)];
    float sg = sgs[b2 * Nn + (Nn - 1)];
    last[(size_t)b2 * 128 + o] = s * (sg + EPSF) + mu;
}

// ---------------------------------------------------------------------------
// Combine +x / -x halves, clamp if all-positive input, emit FLOAT32.
__global__ void combine_kernel(const float* __restrict__ lastc, const float* __restrict__ lasta,
                               const float* __restrict__ ispos, float* __restrict__ out)
{
    int i = blockIdx.x * 256 + threadIdx.x;   // 8192
    int b = i >> 8, t = i & 255;
    float a, an;
    if (t < 128) { a = lastc[b * 128 + t];        an = lastc[(b + 32) * 128 + t]; }
    else         { a = lasta[b * 128 + t - 128];  an = lasta[(b + 32) * 128 + t - 128]; }
    float raw = (a - an) * 0.5f;
    if (ispos[b] > 0.5f) raw = fmaxf(raw, 0.f);
    out[i] = raw;
}

// ---------------------------------------------------------------------------
extern "C" void kernel_launch(void* const* d_in, const int* in_sizes, int n_in,
                              void* d_out, int out_size, void* d_ws, size_t ws_size,
                              hipStream_t stream)
{
    const float* x     = (const float*)d_in[0];   // (32,512,1)
    const float* W_in  = (const float*)d_in[1];   // (64,1024)
    const float* b_in  = (const float*)d_in[2];   // (1024)
    const float* ln1_s = (const float*)d_in[3];   // (8,1024)
    const float* Wqkv  = (const float*)d_in[4];   // (8,1024,3072)
    const float* Wo    = (const float*)d_in[5];   // (8,1024,1024)
    const float* ln2_s = (const float*)d_in[6];   // (8,1024)
    const float* W1    = (const float*)d_in[7];   // (8,1024,4096)
    const float* W2    = (const float*)d_in[8];   // (8,4096,1024)
    const float* lnf_s = (const float*)d_in[9];   // (1024)
    const float* Wout  = (const float*)d_in[10];  // (1024,1280)
    // d_in[11] = Wqs — provably dead for the returned median channel.
    float* out = (float*)d_out;

    float* W = (float*)d_ws;
    size_t off = 0;
    auto alloc = [&](size_t n) { float* p = W + off; off += n; return p; };
    float* ctx_mu = alloc(B2 * NPATCH);
    float* ctx_sg = alloc(B2 * NPATCH);
    float* nmu    = alloc(B2 * MM);
    float* nsg    = alloc(B2 * MM);
    float* ispos  = alloc(32);
    float* normed = alloc(B2 * NPATCH * PP);   // reused (smaller) for AR
    float* hdd    = alloc((size_t)B2 * NPATCH * DD);
    float* xn     = alloc((size_t)B2 * NPATCH * DD);
    float* qkvb   = alloc((size_t)B2 * NPATCH * 3 * DD);
    float* attn   = alloc((size_t)B2 * NPATCH * DD);
    float* ffn    = alloc((size_t)B2 * NPATCH * DFF);
    float* lastc  = alloc(B2 * 128);
    float* lasta  = alloc(B2 * 128);
    float* kcache = alloc((size_t)LL * B2 * HH * CMAX * HD);
    float* vcache = alloc((size_t)LL * B2 * HH * CMAX * HD);
    const size_t cache_l = (size_t)B2 * HH * CMAX * HD;

    // ---------------- context pass: 64 batches x 16 tokens ----------------
    stats_ctx_kernel<<<B2, 64, 0, stream>>>(x, ctx_mu, ctx_sg, ispos, normed);
    {
        int R = B2 * NPATCH;   // 1024 rows
        embed_kernel<<<R, 256, 0, stream>>>(normed, W_in, b_in, hdd);
        for (int l = 0; l < LL; l++) {
            float* kc = kcache + l * cache_l;
            float* vc = vcache + l * cache_l;
            layernorm_kernel<<<R, 256, 0, stream>>>(hdd, xn, ln1_s + l * DD, DD);
            sgemm_kernel<<<dim3(3 * DD / 64, R / 64), 256, 0, stream>>>(
                xn, Wqkv + (size_t)l * DD * 3 * DD, qkvb, R, 3 * DD, DD, 0);
            scatter_kv_kernel<<<(R * DD) / 256, 256, 0, stream>>>(qkvb, kc, vc, NPATCH, 0);
            attn_kernel<<<B2 * HH * NPATCH, 64, 0, stream>>>(qkvb, kc, vc, attn, NPATCH, 0);
            sgemm_kernel<<<dim3(DD / 64, R / 64), 256, 0, stream>>>(
                attn, Wo + (size_t)l * DD * DD, hdd, R, DD, DD, 2);
            layernorm_kernel<<<R, 256, 0, stream>>>(hdd, xn, ln2_s + l * DD, DD);
            sgemm_kernel<<<dim3(DFF / 64, R / 64), 256, 0, stream>>>(
                xn, W1 + (size_t)l * DD * DFF, ffn, R, DFF, DD, 1);
            sgemm_kernel<<<dim3(DD / 64, R / 64), 256, 0, stream>>>(
                ffn, W2 + (size_t)l * DFF * DD, hdd, R, DD, DFF, 2);
        }
        layernorm_kernel<<<R, 256, 0, stream>>>(hdd, xn, lnf_s, DD);
        out5_kernel<<<B2, 128, 0, stream>>>(xn, Wout, ctx_mu, ctx_sg, lastc, NPATCH);
    }

    // ---------------- AR pass: 64 batches x 4 tokens ----------------
    stats_ar_kernel<<<B2, 64, 0, stream>>>(lastc, ctx_mu, ctx_sg, nmu, nsg, normed);
    {
        int R = B2 * MM;       // 256 rows
        embed_kernel<<<R, 256, 0, stream>>>(normed, W_in, b_in, hdd);
        for (int l = 0; l < LL; l++) {
            float* kc = kcache + l * cache_l;
            float* vc = vcache + l * cache_l;
            layernorm_kernel<<<R, 256, 0, stream>>>(hdd, xn, ln1_s + l * DD, DD);
            sgemm_kernel<<<dim3(3 * DD / 64, R / 64), 256, 0, stream>>>(
                xn, Wqkv + (size_t)l * DD * 3 * DD, qkvb, R, 3 * DD, DD, 0);
            scatter_kv_kernel<<<(R * DD) / 256, 256, 0, stream>>>(qkvb, kc, vc, MM, NPATCH);
            attn_kernel<<<B2 * HH * MM, 64, 0, stream>>>(qkvb, kc, vc, attn, MM, NPATCH);
            sgemm_kernel<<<dim3(DD / 64, R / 64), 256, 0, stream>>>(
                attn, Wo + (size_t)l * DD * DD, hdd, R, DD, DD, 2);
            layernorm_kernel<<<R, 256, 0, stream>>>(hdd, xn, ln2_s + l * DD, DD);
            sgemm_kernel<<<dim3(DFF / 64, R / 64), 256, 0, stream>>>(
                xn, W1 + (size_t)l * DD * DFF, ffn, R, DFF, DD, 1);
            sgemm_kernel<<<dim3(DD / 64, R / 64), 256, 0, stream>>>(
                ffn, W2 + (size_t)l * DFF * DD, hdd, R, DD, DFF, 2);
        }
        layernorm_kernel<<<R, 256, 0, stream>>>(hdd, xn, lnf_s, DD);
        out5_kernel<<<B2, 128, 0, stream>>>(xn, Wout, nmu, nsg, lasta, MM);
    }

    // ---------------- combine +x / -x and emit ----------------
    combine_kernel<<<(32 * 256) / 256, 256, 0, stream>>>(lastc, lasta, ispos, out);
}

// Round 3
// 4011.231 us; speedup vs baseline: 3.6234x; 3.6234x over previous
//
#include <hip/hip_runtime.h>
#include <hip/hip_bf16.h>
#include <math.h>

// Model constants
#define PP 32      // patch
#define OO 128     // outputs per patch
#define QQ 10      // quantiles
#define MM 4       // AR patches per step
#define LL 8       // layers
#define HH 16      // heads
#define HD 64      // head dim
#define DD 1024    // D = H*HD
#define DFF 4096
#define NPATCH 16  // context patches (512/32)
#define B2 64      // 32 batches x {+x, -x}
#define CMAX 20    // max cache length
#define EPSF 1e-6f

typedef __attribute__((ext_vector_type(8))) short s16x8;   // 8 bf16 (4 VGPRs)
typedef __attribute__((ext_vector_type(4))) float f32x4;   // MFMA accumulator

// ---------------------------------------------------------------------------
// Running stats (Chan update), context: 16 patches from scratch. Also is_pos.
__global__ void stats_ctx_kernel(const float* __restrict__ x, float* __restrict__ ctx_mu,
                                 float* __restrict__ ctx_sg, float* __restrict__ ispos,
                                 float* __restrict__ normed)
{
    int b2 = blockIdx.x;            // 0..63
    int tid = threadIdx.x;          // 64
    float sign = (b2 < 32) ? 1.f : -1.f;
    const float* xp = x + (size_t)(b2 & 31) * 512;
    __shared__ float smu[NPATCH], ssg[NPATCH];
    if (tid == 0) {
        float n = 0.f, mu = 0.f, sg = 0.f;
        for (int t = 0; t < NPATCH; t++) {
            float s1 = 0.f;
            for (int p = 0; p < PP; p++) s1 += sign * xp[t * PP + p];
            float nn2 = n + 32.f;
            float nmu_ = (n * mu + s1) / nn2;
            float m2 = n * sg * sg;
            for (int p = 0; p < PP; p++) {
                float xv = sign * xp[t * PP + p];
                m2 += (xv - mu) * (xv - nmu_);
            }
            sg = sqrtf(fmaxf(m2 / nn2, 1e-12f));
            mu = nmu_; n = nn2;
            smu[t] = mu; ssg[t] = sg;
            ctx_mu[b2 * NPATCH + t] = mu;
            ctx_sg[b2 * NPATCH + t] = sg;
        }
        if (b2 < 32) {
            int ok = 1;
            for (int i = 0; i < 512; i++) if (xp[i] < 0.f) ok = 0;
            ispos[b2] = (float)ok;
        }
    }
    __syncthreads();
    for (int i = tid; i < 512; i += 64) {
        int t = i >> 5;
        normed[(size_t)b2 * 512 + i] = (sign * xp[i] - smu[t]) / (ssg[t] + EPSF);
    }
}

// AR stats: continue from n=512 state with 4 new patches (= last 128 preds).
__global__ void stats_ar_kernel(const float* __restrict__ lastc, const float* __restrict__ ctx_mu,
                                const float* __restrict__ ctx_sg, float* __restrict__ nmu,
                                float* __restrict__ nsg, float* __restrict__ normed)
{
    int b2 = blockIdx.x;
    int tid = threadIdx.x;
    __shared__ float smu[MM], ssg[MM];
    const float* xp = lastc + (size_t)b2 * 128;
    if (tid == 0) {
        float n = 512.f;
        float mu = ctx_mu[b2 * NPATCH + 15];
        float sg = ctx_sg[b2 * NPATCH + 15];
        for (int t = 0; t < MM; t++) {
            float s1 = 0.f;
            for (int p = 0; p < PP; p++) s1 += xp[t * PP + p];
            float nn2 = n + 32.f;
            float nmu_ = (n * mu + s1) / nn2;
            float m2 = n * sg * sg;
            for (int p = 0; p < PP; p++) {
                float xv = xp[t * PP + p];
                m2 += (xv - mu) * (xv - nmu_);
            }
            sg = sqrtf(fmaxf(m2 / nn2, 1e-12f));
            mu = nmu_; n = nn2;
            smu[t] = mu; ssg[t] = sg;
            nmu[b2 * MM + t] = mu;
            nsg[b2 * MM + t] = sg;
        }
    }
    __syncthreads();
    for (int i = tid; i < 128; i += 64) {
        int t = i >> 5;
        normed[(size_t)b2 * 128 + i] = (xp[i] - smu[t]) / (ssg[t] + EPSF);
    }
}

// ---------------------------------------------------------------------------
// Embedding: hdd[row, :] = normed[row, 0:32] @ W_in[0:32, :] + b_in   (fp32)
__global__ __launch_bounds__(256) void embed_kernel(const float* __restrict__ normed,
                                                    const float* __restrict__ Win,
                                                    const float* __restrict__ bin,
                                                    float* __restrict__ hdd)
{
    int row = blockIdx.x;
    int tid = threadIdx.x;
    __shared__ float p[PP];
    if (tid < PP) p[tid] = normed[(size_t)row * PP + tid];
    __syncthreads();
    for (int c = tid; c < DD; c += 256) {
        float s = bin[c];
        for (int k = 0; k < PP; k++) s = fmaf(p[k], Win[k * DD + c], s);
        hdd[(size_t)row * DD + c] = s;
    }
}

// ---------------------------------------------------------------------------
// LayerNorm: fp32 in -> bf16 out
__global__ __launch_bounds__(256) void layernorm_kernel(const float* __restrict__ in,
                                                        __hip_bfloat16* __restrict__ out,
                                                        const float* __restrict__ scale)
{
    int row = blockIdx.x;
    int tid = threadIdx.x;
    const float* x = in + (size_t)row * DD;
    __hip_bfloat16* o = out + (size_t)row * DD;
    __shared__ float red[256];
    float s = 0.f;
    for (int i = tid; i < DD; i += 256) s += x[i];
    red[tid] = s; __syncthreads();
    for (int st = 128; st > 0; st >>= 1) { if (tid < st) red[tid] += red[tid + st]; __syncthreads(); }
    float m = red[0] / (float)DD;
    __syncthreads();
    float v = 0.f;
    for (int i = tid; i < DD; i += 256) { float d = x[i] - m; v += d * d; }
    red[tid] = v; __syncthreads();
    for (int st = 128; st > 0; st >>= 1) { if (tid < st) red[tid] += red[tid + st]; __syncthreads(); }
    float inv = rsqrtf(red[0] / (float)DD + EPSF);
    for (int i = tid; i < DD; i += 256) o[i] = __float2bfloat16((x[i] - m) * inv * scale[i]);
}

// ---------------------------------------------------------------------------
// Weight transpose: fp32 [R][C] (layer blockIdx.z) -> bf16 [C][R]
__global__ __launch_bounds__(256) void transpose_w(const float* __restrict__ in,
                                                   __hip_bfloat16* __restrict__ out,
                                                   int R, int C)
{
    __shared__ float t[32][33];
    size_t base = (size_t)blockIdx.z * R * C;
    int c0 = blockIdx.x * 32, r0 = blockIdx.y * 32;
    int tx = threadIdx.x & 31, ty = threadIdx.x >> 5;  // 32 x 8
    #pragma unroll
    for (int s = 0; s < 4; s++)
        t[ty + 8 * s][tx] = in[base + (size_t)(r0 + ty + 8 * s) * C + c0 + tx];
    __syncthreads();
    #pragma unroll
    for (int s = 0; s < 4; s++)
        out[base + (size_t)(c0 + ty + 8 * s) * R + r0 + tx] = __float2bfloat16(t[tx][ty + 8 * s]);
}

// Gather Wout quantile-5 columns: w5T[o][k] = Wout[k][o*10+5], bf16
__global__ void w5_kernel(const float* __restrict__ Wout, __hip_bfloat16* __restrict__ w5T)
{
    int i = blockIdx.x * 256 + threadIdx.x;   // 128*1024
    int o = i >> 10, k = i & 1023;
    w5T[i] = __float2bfloat16(Wout[(size_t)k * (OO * QQ) + o * QQ + 5]);
}

// ---------------------------------------------------------------------------
__device__ inline float gelu_tanh(float x)
{
    float x3 = x * x * x;
    float t = tanhf(0.7978845608028654f * (x + 0.044715f * x3));
    return 0.5f * x * (1.f + t);
}

// bf16 MFMA GEMM: C[M,N] = A[M,K] @ BT[N,K]^T
// EP: 0 = store fp32 C; 1 = gelu -> store bf16 Cbf; 2 = C += (residual, fp32)
template<int BM, int BN, int EP>
__global__ __launch_bounds__(256) void hgemm(const __hip_bfloat16* __restrict__ A,
                                             const __hip_bfloat16* __restrict__ BT,
                                             float* __restrict__ C,
                                             __hip_bfloat16* __restrict__ Cbf,
                                             int M, int N, int K)
{
    constexpr int LDK = 40;               // padded k-stride: 80 B rows, 16B-aligned
    constexpr int FM = BM / 32, FN = BN / 32;
    __shared__ __align__(16) short As[BM * LDK];
    __shared__ __align__(16) short Bs[BN * LDK];
    int tid = threadIdx.x;
    int lane = tid & 63, wave = tid >> 6;
    int wm = (wave >> 1) * (BM / 2), wn = (wave & 1) * (BN / 2);
    int lm = lane & 15, quad = lane >> 4;
    int row0 = blockIdx.y * BM, col0 = blockIdx.x * BN;

    f32x4 ac[FM][FN];
    #pragma unroll
    for (int i = 0; i < FM; i++)
        #pragma unroll
        for (int j = 0; j < FN; j++) ac[i][j] = (f32x4){0.f, 0.f, 0.f, 0.f};

    for (int k0 = 0; k0 < K; k0 += 32) {
        #pragma unroll
        for (int ch = tid; ch < BM * 4; ch += 256) {
            int r = ch >> 2, kc = (ch & 3) * 8;
            *(uint4*)&As[r * LDK + kc] = *(const uint4*)(A + (size_t)(row0 + r) * K + k0 + kc);
        }
        #pragma unroll
        for (int ch = tid; ch < BN * 4; ch += 256) {
            int r = ch >> 2, kc = (ch & 3) * 8;
            *(uint4*)&Bs[r * LDK + kc] = *(const uint4*)(BT + (size_t)(col0 + r) * K + k0 + kc);
        }
        __syncthreads();
        s16x8 af[FM], bfr[FN];
        #pragma unroll
        for (int i = 0; i < FM; i++) af[i] = *(const s16x8*)&As[(wm + i * 16 + lm) * LDK + quad * 8];
        #pragma unroll
        for (int j = 0; j < FN; j++) bfr[j] = *(const s16x8*)&Bs[(wn + j * 16 + lm) * LDK + quad * 8];
        #pragma unroll
        for (int i = 0; i < FM; i++)
            #pragma unroll
            for (int j = 0; j < FN; j++)
                ac[i][j] = __builtin_amdgcn_mfma_f32_16x16x32_bf16(af[i], bfr[j], ac[i][j], 0, 0, 0);
        __syncthreads();
    }
    #pragma unroll
    for (int i = 0; i < FM; i++) {
        #pragma unroll
        for (int j = 0; j < FN; j++) {
            #pragma unroll
            for (int r = 0; r < 4; r++) {
                int rr = row0 + wm + i * 16 + quad * 4 + r;
                int cc = col0 + wn + j * 16 + lm;
                size_t idx = (size_t)rr * N + cc;
                float v = ac[i][j][r];
                if (EP == 0)      C[idx] = v;
                else if (EP == 1) Cbf[idx] = __float2bfloat16(gelu_tanh(v));
                else              C[idx] += v;
            }
        }
    }
}

// ---------------------------------------------------------------------------
// Scatter K,V (fp32 qkv) into bf16 per-layer caches (b, h, CMAX, HD)
__global__ void scatter_kv_kernel(const float* __restrict__ qkv, __hip_bfloat16* __restrict__ Kc,
                                  __hip_bfloat16* __restrict__ Vc, int Nn, int off)
{
    int idx = blockIdx.x * 256 + threadIdx.x;   // rows * 1024 total
    int row = idx >> 10, col = idx & 1023;
    int b = row / Nn, n = row % Nn;
    int h = col >> 6, hd = col & 63;
    size_t dst = (((size_t)(b * HH + h) * CMAX) + off + n) * HD + hd;
    Kc[dst] = __float2bfloat16(qkv[(size_t)row * 3072 + 1024 + col]);
    Vc[dst] = __float2bfloat16(qkv[(size_t)row * 3072 + 2048 + col]);
}

// ---------------------------------------------------------------------------
// Attention: one wave per (b, h, n). Causal over len = n + off + 1 cache rows.
__global__ __launch_bounds__(64) void attn_kernel(const float* __restrict__ qkv,
                                                  const __hip_bfloat16* __restrict__ Kc,
                                                  const __hip_bfloat16* __restrict__ Vc,
                                                  __hip_bfloat16* __restrict__ outb, int Nn, int off)
{
    int gid = blockIdx.x;
    int n = gid % Nn;
    int h = (gid / Nn) & (HH - 1);
    int b = gid / (Nn * HH);
    int lane = threadIdx.x;
    int len = n + off + 1;
    const float* q = qkv + ((size_t)(b * Nn + n)) * 3072 + h * HD;
    const __hip_bfloat16* Kb = Kc + ((size_t)(b * HH + h)) * CMAX * HD;
    const __hip_bfloat16* Vb = Vc + ((size_t)(b * HH + h)) * CMAX * HD;

    float score = -1e30f;
    if (lane < len) {
        const __hip_bfloat16* kr = Kb + lane * HD;
        float s = 0.f;
        for (int d = 0; d < HD; d++) s = fmaf(q[d], __bfloat162float(kr[d]), s);
        score = s * 0.125f;   // 1/sqrt(64)
    }
    float mx = score;
    for (int o = 32; o > 0; o >>= 1) mx = fmaxf(mx, __shfl_xor(mx, o, 64));
    float e = (lane < len) ? expf(score - mx) : 0.f;
    float sm = e;
    for (int o = 32; o > 0; o >>= 1) sm += __shfl_xor(sm, o, 64);
    float att = e / sm;
    __shared__ float satt[64];
    satt[lane] = att;
    __syncthreads();
    float acc = 0.f;
    for (int m = 0; m < len; m++) acc = fmaf(satt[m], __bfloat162float(Vb[m * HD + lane]), acc);
    outb[((size_t)(b * Nn + n)) * DD + h * HD + lane] = __float2bfloat16(acc);
}

// ---------------------------------------------------------------------------
// Final head: quantile-5 columns only; + revin. One block per b2.
__global__ __launch_bounds__(128) void out5_kernel(const __hip_bfloat16* __restrict__ xn,
                                                   const __hip_bfloat16* __restrict__ w5T,
                                                   const float* __restrict__ mus,
                                                   const float* __restrict__ sgs,
                                                   float* __restrict__ last, int Nn)
{
    int b2 = blockIdx.x;
    int o = threadIdx.x;          // 0..127
    const __hip_bfloat16* xr = xn + (size_t)(b2 * Nn + Nn - 1) * DD;
    const __hip_bfloat16* w = w5T + (size_t)o * DD;
    float s = 0.f;
    for (int k = 0; k < DD; k++) s = fmaf(__bfloat162float(xr[k]), __bfloat162float(w[k]), s);
    float mu = mus[b2 * Nn + (Nn - 1)];
    float sg = sgs[b2 * Nn + (Nn - 1)];
    last[(size_t)b2 * 128 + o] = s * (sg + EPSF) + mu;
}

// ---------------------------------------------------------------------------
// Combine +x / -x halves, clamp if all-positive input, emit FLOAT32.
__global__ void combine_kernel(const float* __restrict__ lastc, const float* __restrict__ lasta,
                               const float* __restrict__ ispos, float* __restrict__ out)
{
    int i = blockIdx.x * 256 + threadIdx.x;   // 8192
    int b = i >> 8, t = i & 255;
    float a, an;
    if (t < 128) { a = lastc[b * 128 + t];        an = lastc[(b + 32) * 128 + t]; }
    else         { a = lasta[b * 128 + t - 128];  an = lasta[(b + 32) * 128 + t - 128]; }
    float raw = (a - an) * 0.5f;
    if (ispos[b] > 0.5f) raw = fmaxf(raw, 0.f);
    out[i] = raw;
}

// ---------------------------------------------------------------------------
extern "C" void kernel_launch(void* const* d_in, const int* in_sizes, int n_in,
                              void* d_out, int out_size, void* d_ws, size_t ws_size,
                              hipStream_t stream)
{
    (void)in_sizes; (void)n_in; (void)out_size;
    const float* x     = (const float*)d_in[0];
    const float* W_in  = (const float*)d_in[1];
    const float* b_in  = (const float*)d_in[2];
    const float* ln1_s = (const float*)d_in[3];
    const float* Wqkv  = (const float*)d_in[4];   // (8,1024,3072)
    const float* Wo    = (const float*)d_in[5];   // (8,1024,1024)
    const float* ln2_s = (const float*)d_in[6];
    const float* W1    = (const float*)d_in[7];   // (8,1024,4096)
    const float* W2    = (const float*)d_in[8];   // (8,4096,1024)
    const float* lnf_s = (const float*)d_in[9];
    const float* Wout  = (const float*)d_in[10];  // (1024,1280)
    float* out = (float*)d_out;

    size_t off = 0;
    auto alloc = [&](size_t bytes) {
        char* p = (char*)d_ws + off;
        off = (off + bytes + 255) & ~(size_t)255;
        return (void*)p;
    };
    typedef __hip_bfloat16 bf16;
    float* ctx_mu = (float*)alloc(B2 * NPATCH * 4);
    float* ctx_sg = (float*)alloc(B2 * NPATCH * 4);
    float* nmu    = (float*)alloc(B2 * MM * 4);
    float* nsg    = (float*)alloc(B2 * MM * 4);
    float* ispos  = (float*)alloc(32 * 4);
    float* normed = (float*)alloc(B2 * NPATCH * PP * 4);
    float* lastc  = (float*)alloc(B2 * 128 * 4);
    float* lasta  = (float*)alloc(B2 * 128 * 4);
    float* hdd    = (float*)alloc((size_t)B2 * NPATCH * DD * 4);
    float* qkvb   = (float*)alloc((size_t)B2 * NPATCH * 3 * DD * 4);
    bf16* xn      = (bf16*)alloc((size_t)B2 * NPATCH * DD * 2);
    bf16* attnb   = (bf16*)alloc((size_t)B2 * NPATCH * DD * 2);
    bf16* ffnb    = (bf16*)alloc((size_t)B2 * NPATCH * DFF * 2);
    const size_t cache_l = (size_t)B2 * HH * CMAX * HD;
    bf16* kcache  = (bf16*)alloc(LL * cache_l * 2);
    bf16* vcache  = (bf16*)alloc(LL * cache_l * 2);
    bf16* w5T     = (bf16*)alloc((size_t)OO * DD * 2);

    const size_t szQKV = (size_t)DD * 3 * DD;     // per-layer elems
    const size_t szWO  = (size_t)DD * DD;
    const size_t szW1  = (size_t)DD * DFF;
    const size_t szW2  = (size_t)DFF * DD;
    const size_t WBYTES = (szQKV + szWO + szW1 + szW2) * LL * 2 + 4096;
    bool big = (off + WBYTES) <= ws_size;

    bf16 *wqkvT = nullptr, *woT = nullptr, *w1T = nullptr, *w2T = nullptr, *rot = nullptr;
    if (big) {
        wqkvT = (bf16*)alloc(LL * szQKV * 2);
        woT   = (bf16*)alloc(LL * szWO * 2);
        w1T   = (bf16*)alloc(LL * szW1 * 2);
        w2T   = (bf16*)alloc(LL * szW2 * 2);
        transpose_w<<<dim3(3072 / 32, 1024 / 32, LL), 256, 0, stream>>>(Wqkv, wqkvT, 1024, 3072);
        transpose_w<<<dim3(1024 / 32, 1024 / 32, LL), 256, 0, stream>>>(Wo, woT, 1024, 1024);
        transpose_w<<<dim3(4096 / 32, 1024 / 32, LL), 256, 0, stream>>>(W1, w1T, 1024, 4096);
        transpose_w<<<dim3(1024 / 32, 4096 / 32, LL), 256, 0, stream>>>(W2, w2T, 4096, 1024);
    } else {
        rot = (bf16*)alloc(szW1 * 2);   // largest slice; stream order serializes reuse
    }
    w5_kernel<<<(OO * DD) / 256, 256, 0, stream>>>(Wout, w5T);

    // ---------------- context pass: 64 batches x 16 tokens ----------------
    stats_ctx_kernel<<<B2, 64, 0, stream>>>(x, ctx_mu, ctx_sg, ispos, normed);
    {
        const int R = B2 * NPATCH;   // 1024 rows
        embed_kernel<<<R, 256, 0, stream>>>(normed, W_in, b_in, hdd);
        for (int l = 0; l < LL; l++) {
            bf16* kc = kcache + l * cache_l;
            bf16* vc = vcache + l * cache_l;
            layernorm_kernel<<<R, 256, 0, stream>>>(hdd, xn, ln1_s + l * DD);
            bf16* bq;
            if (big) bq = wqkvT + l * szQKV;
            else { transpose_w<<<dim3(96, 32, 1), 256, 0, stream>>>(Wqkv + l * szQKV, rot, 1024, 3072); bq = rot; }
            hgemm<128, 128, 0><<<dim3(3072 / 128, R / 128), 256, 0, stream>>>(xn, bq, qkvb, nullptr, R, 3072, 1024);
            scatter_kv_kernel<<<(R * DD) / 256, 256, 0, stream>>>(qkvb, kc, vc, NPATCH, 0);
            attn_kernel<<<B2 * HH * NPATCH, 64, 0, stream>>>(qkvb, kc, vc, attnb, NPATCH, 0);
            bf16* bo;
            if (big) bo = woT + l * szWO;
            else { transpose_w<<<dim3(32, 32, 1), 256, 0, stream>>>(Wo + l * szWO, rot, 1024, 1024); bo = rot; }
            hgemm<128, 64, 2><<<dim3(1024 / 64, R / 128), 256, 0, stream>>>(attnb, bo, hdd, nullptr, R, 1024, 1024);
            layernorm_kernel<<<R, 256, 0, stream>>>(hdd, xn, ln2_s + l * DD);
            bf16* b1;
            if (big) b1 = w1T + l * szW1;
            else { transpose_w<<<dim3(128, 32, 1), 256, 0, stream>>>(W1 + l * szW1, rot, 1024, 4096); b1 = rot; }
            hgemm<128, 128, 1><<<dim3(4096 / 128, R / 128), 256, 0, stream>>>(xn, b1, nullptr, ffnb, R, 4096, 1024);
            bf16* b2;
            if (big) b2 = w2T + l * szW2;
            else { transpose_w<<<dim3(32, 128, 1), 256, 0, stream>>>(W2 + l * szW2, rot, 4096, 1024); b2 = rot; }
            hgemm<128, 64, 2><<<dim3(1024 / 64, R / 128), 256, 0, stream>>>(ffnb, b2, hdd, nullptr, R, 1024, 4096);
        }
        layernorm_kernel<<<R, 256, 0, stream>>>(hdd, xn, lnf_s);
        out5_kernel<<<B2, 128, 0, stream>>>(xn, w5T, ctx_mu, ctx_sg, lastc, NPATCH);
    }

    // ---------------- AR pass: 64 batches x 4 tokens ----------------
    stats_ar_kernel<<<B2, 64, 0, stream>>>(lastc, ctx_mu, ctx_sg, nmu, nsg, normed);
    {
        const int R = B2 * MM;       // 256 rows
        embed_kernel<<<R, 256, 0, stream>>>(normed, W_in, b_in, hdd);
        for (int l = 0; l < LL; l++) {
            bf16* kc = kcache + l * cache_l;
            bf16* vc = vcache + l * cache_l;
            layernorm_kernel<<<R, 256, 0, stream>>>(hdd, xn, ln1_s + l * DD);
            bf16* bq;
            if (big) bq = wqkvT + l * szQKV;
            else { transpose_w<<<dim3(96, 32, 1), 256, 0, stream>>>(Wqkv + l * szQKV, rot, 1024, 3072); bq = rot; }
            hgemm<64, 128, 0><<<dim3(3072 / 128, R / 64), 256, 0, stream>>>(xn, bq, qkvb, nullptr, R, 3072, 1024);
            scatter_kv_kernel<<<(R * DD) / 256, 256, 0, stream>>>(qkvb, kc, vc, MM, NPATCH);
            attn_kernel<<<B2 * HH * MM, 64, 0, stream>>>(qkvb, kc, vc, attnb, MM, NPATCH);
            bf16* bo;
            if (big) bo = woT + l * szWO;
            else { transpose_w<<<dim3(32, 32, 1), 256, 0, stream>>>(Wo + l * szWO, rot, 1024, 1024); bo = rot; }
            hgemm<64, 64, 2><<<dim3(1024 / 64, R / 64), 256, 0, stream>>>(attnb, bo, hdd, nullptr, R, 1024, 1024);
            layernorm_kernel<<<R, 256, 0, stream>>>(hdd, xn, ln2_s + l * DD);
            bf16* b1;
            if (big) b1 = w1T + l * szW1;
            else { transpose_w<<<dim3(128, 32, 1), 256, 0, stream>>>(W1 + l * szW1, rot, 1024, 4096); b1 = rot; }
            hgemm<64, 128, 1><<<dim3(4096 / 128, R / 64), 256, 0, stream>>>(xn, b1, nullptr, ffnb, R, 4096, 1024);
            bf16* b2;
            if (big) b2 = w2T + l * szW2;
            else { transpose_w<<<dim3(32, 128, 1), 256, 0, stream>>>(W2 + l * szW2, rot, 4096, 1024); b2 = rot; }
            hgemm<64, 64, 2><<<dim3(1024 / 64, R / 64), 256, 0, stream>>>(ffnb, b2, hdd, nullptr, R, 1024, 4096);
        }
        layernorm_kernel<<<R, 256, 0, stream>>>(hdd, xn, lnf_s);
        out5_kernel<<<B2, 128, 0, stream>>>(xn, w5T, nmu, nsg, lasta, MM);
    }

    // ---------------- combine +x / -x and emit ----------------
    combine_kernel<<<(32 * 256) / 256, 256, 0, stream>>>(lastc, lasta, ispos, out);
}

// Round 4
// 2171.918 us; speedup vs baseline: 6.6919x; 1.8469x over previous
//
#include <hip/hip_runtime.h>
#include <hip/hip_bf16.h>
#include <math.h>

// Model constants
#define PP 32      // patch
#define OO 128     // outputs per patch
#define QQ 10      // quantiles
#define MM 4       // AR patches per step
#define LL 8       // layers
#define HH 16      // heads
#define HD 64      // head dim
#define DD 1024    // D = H*HD
#define DFF 4096
#define NPATCH 16  // context patches (512/32)
#define B2 64      // 32 batches x {+x, -x}
#define CMAX 20    // max cache length
#define EPSF 1e-6f

typedef __attribute__((ext_vector_type(8))) short s16x8;   // 8 bf16 (4 VGPRs)
typedef __attribute__((ext_vector_type(4))) float f32x4;   // MFMA accumulator
typedef __hip_bfloat16 bf16;

// Async global->LDS, 16 B per lane. LDS dest = wave-uniform base + lane*16.
__device__ inline void ld_lds16(void* lds_base, const void* gaddr)
{
    __builtin_amdgcn_global_load_lds(
        (const __attribute__((address_space(1))) unsigned int*)gaddr,
        (__attribute__((address_space(3))) unsigned int*)lds_base, 16, 0, 0);
}

// ---------------------------------------------------------------------------
// Running stats (Chan update), context: 16 patches from scratch. Also is_pos.
__global__ void stats_ctx_kernel(const float* __restrict__ x, float* __restrict__ ctx_mu,
                                 float* __restrict__ ctx_sg, float* __restrict__ ispos,
                                 float* __restrict__ normed)
{
    int b2 = blockIdx.x;            // 0..63
    int tid = threadIdx.x;          // 64
    float sign = (b2 < 32) ? 1.f : -1.f;
    const float* xp = x + (size_t)(b2 & 31) * 512;
    __shared__ float smu[NPATCH], ssg[NPATCH];
    if (tid == 0) {
        float n = 0.f, mu = 0.f, sg = 0.f;
        for (int t = 0; t < NPATCH; t++) {
            float s1 = 0.f;
            for (int p = 0; p < PP; p++) s1 += sign * xp[t * PP + p];
            float nn2 = n + 32.f;
            float nmu_ = (n * mu + s1) / nn2;
            float m2 = n * sg * sg;
            for (int p = 0; p < PP; p++) {
                float xv = sign * xp[t * PP + p];
                m2 += (xv - mu) * (xv - nmu_);
            }
            sg = sqrtf(fmaxf(m2 / nn2, 1e-12f));
            mu = nmu_; n = nn2;
            smu[t] = mu; ssg[t] = sg;
            ctx_mu[b2 * NPATCH + t] = mu;
            ctx_sg[b2 * NPATCH + t] = sg;
        }
        if (b2 < 32) {
            int ok = 1;
            for (int i = 0; i < 512; i++) if (xp[i] < 0.f) ok = 0;
            ispos[b2] = (float)ok;
        }
    }
    __syncthreads();
    for (int i = tid; i < 512; i += 64) {
        int t = i >> 5;
        normed[(size_t)b2 * 512 + i] = (sign * xp[i] - smu[t]) / (ssg[t] + EPSF);
    }
}

// AR stats: continue from n=512 state with 4 new patches (= last 128 preds).
__global__ void stats_ar_kernel(const float* __restrict__ lastc, const float* __restrict__ ctx_mu,
                                const float* __restrict__ ctx_sg, float* __restrict__ nmu,
                                float* __restrict__ nsg, float* __restrict__ normed)
{
    int b2 = blockIdx.x;
    int tid = threadIdx.x;
    __shared__ float smu[MM], ssg[MM];
    const float* xp = lastc + (size_t)b2 * 128;
    if (tid == 0) {
        float n = 512.f;
        float mu = ctx_mu[b2 * NPATCH + 15];
        float sg = ctx_sg[b2 * NPATCH + 15];
        for (int t = 0; t < MM; t++) {
            float s1 = 0.f;
            for (int p = 0; p < PP; p++) s1 += xp[t * PP + p];
            float nn2 = n + 32.f;
            float nmu_ = (n * mu + s1) / nn2;
            float m2 = n * sg * sg;
            for (int p = 0; p < PP; p++) {
                float xv = xp[t * PP + p];
                m2 += (xv - mu) * (xv - nmu_);
            }
            sg = sqrtf(fmaxf(m2 / nn2, 1e-12f));
            mu = nmu_; n = nn2;
            smu[t] = mu; ssg[t] = sg;
            nmu[b2 * MM + t] = mu;
            nsg[b2 * MM + t] = sg;
        }
    }
    __syncthreads();
    for (int i = tid; i < 128; i += 64) {
        int t = i >> 5;
        normed[(size_t)b2 * 128 + i] = (xp[i] - smu[t]) / (ssg[t] + EPSF);
    }
}

// ---------------------------------------------------------------------------
// Embedding: hdd[row, :] = normed[row, 0:32] @ W_in[0:32, :] + b_in   (fp32)
__global__ __launch_bounds__(256) void embed_kernel(const float* __restrict__ normed,
                                                    const float* __restrict__ Win,
                                                    const float* __restrict__ bin,
                                                    float* __restrict__ hdd)
{
    int row = blockIdx.x;
    int tid = threadIdx.x;
    __shared__ float p[PP];
    if (tid < PP) p[tid] = normed[(size_t)row * PP + tid];
    __syncthreads();
    for (int c = tid; c < DD; c += 256) {
        float s = bin[c];
        for (int k = 0; k < PP; k++) s = fmaf(p[k], Win[k * DD + c], s);
        hdd[(size_t)row * DD + c] = s;
    }
}

// ---------------------------------------------------------------------------
// LayerNorm: fp32 in -> bf16 out
__global__ __launch_bounds__(256) void layernorm_kernel(const float* __restrict__ in,
                                                        bf16* __restrict__ out,
                                                        const float* __restrict__ scale)
{
    int row = blockIdx.x;
    int tid = threadIdx.x;
    const float* x = in + (size_t)row * DD;
    bf16* o = out + (size_t)row * DD;
    __shared__ float red[256];
    float s = 0.f;
    for (int i = tid; i < DD; i += 256) s += x[i];
    red[tid] = s; __syncthreads();
    for (int st = 128; st > 0; st >>= 1) { if (tid < st) red[tid] += red[tid + st]; __syncthreads(); }
    float m = red[0] / (float)DD;
    __syncthreads();
    float v = 0.f;
    for (int i = tid; i < DD; i += 256) { float d = x[i] - m; v += d * d; }
    red[tid] = v; __syncthreads();
    for (int st = 128; st > 0; st >>= 1) { if (tid < st) red[tid] += red[tid + st]; __syncthreads(); }
    float inv = rsqrtf(red[0] / (float)DD + EPSF);
    for (int i = tid; i < DD; i += 256) o[i] = __float2bfloat16((x[i] - m) * inv * scale[i]);
}

// ---------------------------------------------------------------------------
// Weight transpose: fp32 [R][C] (layer blockIdx.z) -> bf16 [C][R]
__global__ __launch_bounds__(256) void transpose_w(const float* __restrict__ in,
                                                   bf16* __restrict__ out,
                                                   int R, int C)
{
    __shared__ float t[32][33];
    size_t base = (size_t)blockIdx.z * R * C;
    int c0 = blockIdx.x * 32, r0 = blockIdx.y * 32;
    int tx = threadIdx.x & 31, ty = threadIdx.x >> 5;  // 32 x 8
    #pragma unroll
    for (int s = 0; s < 4; s++)
        t[ty + 8 * s][tx] = in[base + (size_t)(r0 + ty + 8 * s) * C + c0 + tx];
    __syncthreads();
    #pragma unroll
    for (int s = 0; s < 4; s++)
        out[base + (size_t)(c0 + ty + 8 * s) * R + r0 + tx] = __float2bfloat16(t[tx][ty + 8 * s]);
}

// Gather Wout quantile-5 columns: w5T[o][k] = Wout[k][o*10+5], bf16
__global__ void w5_kernel(const float* __restrict__ Wout, bf16* __restrict__ w5T)
{
    int i = blockIdx.x * 256 + threadIdx.x;   // 128*1024
    int o = i >> 10, k = i & 1023;
    w5T[i] = __float2bfloat16(Wout[(size_t)k * (OO * QQ) + o * QQ + 5]);
}

__global__ void zero_kernel(float* __restrict__ p, int n)
{
    int i = blockIdx.x * 256 + threadIdx.x;
    if (i < n) p[i] = 0.f;
}

// ---------------------------------------------------------------------------
__device__ inline float gelu_tanh(float x)
{
    float x3 = x * x * x;
    float t = tanhf(0.7978845608028654f * (x + 0.044715f * x3));
    return 0.5f * x * (1.f + t);
}

// bf16 MFMA GEMM with async LDS staging + split-K (blockIdx.z over Kpart).
// C[M,N] = A[M,K] @ BT[N,K]^T
// EP: 0 = store fp32 (atomicAdd if gridDim.z>1); 1 = gelu -> bf16; 2 = atomicAdd (residual)
template<int BM, int BN, int EP>
__global__ __launch_bounds__(256) void hgemm(const bf16* __restrict__ A,
                                             const bf16* __restrict__ BT,
                                             float* __restrict__ C,
                                             bf16* __restrict__ Cbf,
                                             int M, int N, int K, int Kpart)
{
    constexpr int FM = BM / 32, FN = BN / 32;      // frags per wave (2x2 wave grid)
    __shared__ __align__(16) short As[BM * 32];    // [BM][32] bf16, rows = 64 B
    __shared__ __align__(16) short Bs[BN * 32];
    int tid = threadIdx.x;
    int lane = tid & 63, wave = tid >> 6;
    int wm = (wave >> 1) * (BM / 2), wn = (wave & 1) * (BN / 2);
    int lm = lane & 15, quad = lane >> 4;
    int row0 = blockIdx.y * BM, col0 = blockIdx.x * BN;
    int kb = blockIdx.z * Kpart, ke = kb + Kpart;
    int ar = lane >> 2;          // row within 16-row chunk
    int ak = (lane & 3) * 8;     // k-offset (shorts) within row

    f32x4 ac[FM][FN];
    #pragma unroll
    for (int i = 0; i < FM; i++)
        #pragma unroll
        for (int j = 0; j < FN; j++) ac[i][j] = (f32x4){0.f, 0.f, 0.f, 0.f};

    for (int k0 = kb; k0 < ke; k0 += 32) {
        #pragma unroll
        for (int c = 0; c < BM / 64; c++) {
            int chunk = wave + 4 * c;   // 16 rows, 1 KB
            ld_lds16(&As[chunk * 512], A + (size_t)(row0 + chunk * 16 + ar) * K + k0 + ak);
        }
        #pragma unroll
        for (int c = 0; c < BN / 64; c++) {
            int chunk = wave + 4 * c;
            ld_lds16(&Bs[chunk * 512], BT + (size_t)(col0 + chunk * 16 + ar) * K + k0 + ak);
        }
        __syncthreads();               // drains vmcnt (async LDS) before reads
        s16x8 af[FM], bfr[FN];
        #pragma unroll
        for (int i = 0; i < FM; i++) af[i] = *(const s16x8*)&As[(wm + i * 16 + lm) * 32 + quad * 8];
        #pragma unroll
        for (int j = 0; j < FN; j++) bfr[j] = *(const s16x8*)&Bs[(wn + j * 16 + lm) * 32 + quad * 8];
        #pragma unroll
        for (int i = 0; i < FM; i++)
            #pragma unroll
            for (int j = 0; j < FN; j++)
                ac[i][j] = __builtin_amdgcn_mfma_f32_16x16x32_bf16(af[i], bfr[j], ac[i][j], 0, 0, 0);
        __syncthreads();
    }
    bool multi = (gridDim.z > 1);
    #pragma unroll
    for (int i = 0; i < FM; i++) {
        #pragma unroll
        for (int j = 0; j < FN; j++) {
            #pragma unroll
            for (int r = 0; r < 4; r++) {
                int rr = row0 + wm + i * 16 + quad * 4 + r;
                int cc = col0 + wn + j * 16 + lm;
                size_t idx = (size_t)rr * N + cc;
                float v = ac[i][j][r];
                if (EP == 0) { if (multi) atomicAdd(&C[idx], v); else C[idx] = v; }
                else if (EP == 1) Cbf[idx] = __float2bfloat16(gelu_tanh(v));
                else atomicAdd(&C[idx], v);
            }
        }
    }
}

// ---------------------------------------------------------------------------
// Scatter K,V (fp32 qkv) into bf16 per-layer caches (b, h, CMAX, HD)
__global__ void scatter_kv_kernel(const float* __restrict__ qkv, bf16* __restrict__ Kc,
                                  bf16* __restrict__ Vc, int Nn, int off)
{
    int idx = blockIdx.x * 256 + threadIdx.x;   // rows * 1024 total
    int row = idx >> 10, col = idx & 1023;
    int b = row / Nn, n = row % Nn;
    int h = col >> 6, hd = col & 63;
    size_t dst = (((size_t)(b * HH + h) * CMAX) + off + n) * HD + hd;
    Kc[dst] = __float2bfloat16(qkv[(size_t)row * 3072 + 1024 + col]);
    Vc[dst] = __float2bfloat16(qkv[(size_t)row * 3072 + 2048 + col]);
}

// ---------------------------------------------------------------------------
// Attention: one wave per (b, h, n). Causal over len = n + off + 1 cache rows.
__global__ __launch_bounds__(64) void attn_kernel(const float* __restrict__ qkv,
                                                  const bf16* __restrict__ Kc,
                                                  const bf16* __restrict__ Vc,
                                                  bf16* __restrict__ outb, int Nn, int off)
{
    int gid = blockIdx.x;
    int n = gid % Nn;
    int h = (gid / Nn) & (HH - 1);
    int b = gid / (Nn * HH);
    int lane = threadIdx.x;
    int len = n + off + 1;
    const float* q = qkv + ((size_t)(b * Nn + n)) * 3072 + h * HD;
    const bf16* Kb = Kc + ((size_t)(b * HH + h)) * CMAX * HD;
    const bf16* Vb = Vc + ((size_t)(b * HH + h)) * CMAX * HD;

    float score = -1e30f;
    if (lane < len) {
        const bf16* kr = Kb + lane * HD;
        float s = 0.f;
        for (int d = 0; d < HD; d++) s = fmaf(q[d], __bfloat162float(kr[d]), s);
        score = s * 0.125f;   // 1/sqrt(64)
    }
    float mx = score;
    for (int o = 32; o > 0; o >>= 1) mx = fmaxf(mx, __shfl_xor(mx, o, 64));
    float e = (lane < len) ? expf(score - mx) : 0.f;
    float sm = e;
    for (int o = 32; o > 0; o >>= 1) sm += __shfl_xor(sm, o, 64);
    float att = e / sm;
    __shared__ float satt[64];
    satt[lane] = att;
    __syncthreads();
    float acc = 0.f;
    for (int m = 0; m < len; m++) acc = fmaf(satt[m], __bfloat162float(Vb[m * HD + lane]), acc);
    outb[((size_t)(b * Nn + n)) * DD + h * HD + lane] = __float2bfloat16(acc);
}

// ---------------------------------------------------------------------------
// Final head: quantile-5 columns only; + revin. One block per b2.
__global__ __launch_bounds__(128) void out5_kernel(const bf16* __restrict__ xn,
                                                   const bf16* __restrict__ w5T,
                                                   const float* __restrict__ mus,
                                                   const float* __restrict__ sgs,
                                                   float* __restrict__ last, int Nn)
{
    int b2 = blockIdx.x;
    int o = threadIdx.x;          // 0..127
    const bf16* xr = xn + (size_t)(b2 * Nn + Nn - 1) * DD;
    const bf16* w = w5T + (size_t)o * DD;
    float s = 0.f;
    for (int k = 0; k < DD; k++) s = fmaf(__bfloat162float(xr[k]), __bfloat162float(w[k]), s);
    float mu = mus[b2 * Nn + (Nn - 1)];
    float sg = sgs[b2 * Nn + (Nn - 1)];
    last[(size_t)b2 * 128 + o] = s * (sg + EPSF) + mu;
}

// ---------------------------------------------------------------------------
// Combine +x / -x halves, clamp if all-positive input, emit FLOAT32.
__global__ void combine_kernel(const float* __restrict__ lastc, const float* __restrict__ lasta,
                               const float* __restrict__ ispos, float* __restrict__ out)
{
    int i = blockIdx.x * 256 + threadIdx.x;   // 8192
    int b = i >> 8, t = i & 255;
    float a, an;
    if (t < 128) { a = lastc[b * 128 + t];        an = lastc[(b + 32) * 128 + t]; }
    else         { a = lasta[b * 128 + t - 128];  an = lasta[(b + 32) * 128 + t - 128]; }
    float raw = (a - an) * 0.5f;
    if (ispos[b] > 0.5f) raw = fmaxf(raw, 0.f);
    out[i] = raw;
}

// ---------------------------------------------------------------------------
extern "C" void kernel_launch(void* const* d_in, const int* in_sizes, int n_in,
                              void* d_out, int out_size, void* d_ws, size_t ws_size,
                              hipStream_t stream)
{
    (void)in_sizes; (void)n_in; (void)out_size;
    const float* x     = (const float*)d_in[0];
    const float* W_in  = (const float*)d_in[1];
    const float* b_in  = (const float*)d_in[2];
    const float* ln1_s = (const float*)d_in[3];
    const float* Wqkv  = (const float*)d_in[4];   // (8,1024,3072)
    const float* Wo    = (const float*)d_in[5];   // (8,1024,1024)
    const float* ln2_s = (const float*)d_in[6];
    const float* W1    = (const float*)d_in[7];   // (8,1024,4096)
    const float* W2    = (const float*)d_in[8];   // (8,4096,1024)
    const float* lnf_s = (const float*)d_in[9];
    const float* Wout  = (const float*)d_in[10];  // (1024,1280)
    float* out = (float*)d_out;

    size_t off = 0;
    auto alloc = [&](size_t bytes) {
        char* p = (char*)d_ws + off;
        off = (off + bytes + 255) & ~(size_t)255;
        return (void*)p;
    };
    float* ctx_mu = (float*)alloc(B2 * NPATCH * 4);
    float* ctx_sg = (float*)alloc(B2 * NPATCH * 4);
    float* nmu    = (float*)alloc(B2 * MM * 4);
    float* nsg    = (float*)alloc(B2 * MM * 4);
    float* ispos  = (float*)alloc(32 * 4);
    float* normed = (float*)alloc(B2 * NPATCH * PP * 4);
    float* lastc  = (float*)alloc(B2 * 128 * 4);
    float* lasta  = (float*)alloc(B2 * 128 * 4);
    float* hdd    = (float*)alloc((size_t)B2 * NPATCH * DD * 4);
    float* qkvb   = (float*)alloc((size_t)B2 * NPATCH * 3 * DD * 4);
    bf16* xn      = (bf16*)alloc((size_t)B2 * NPATCH * DD * 2);
    bf16* attnb   = (bf16*)alloc((size_t)B2 * NPATCH * DD * 2);
    bf16* ffnb    = (bf16*)alloc((size_t)B2 * NPATCH * DFF * 2);
    const size_t cache_l = (size_t)B2 * HH * CMAX * HD;
    bf16* kcache  = (bf16*)alloc(LL * cache_l * 2);
    bf16* vcache  = (bf16*)alloc(LL * cache_l * 2);
    bf16* w5T     = (bf16*)alloc((size_t)OO * DD * 2);

    const size_t szQKV = (size_t)DD * 3 * DD;     // per-layer elems
    const size_t szWO  = (size_t)DD * DD;
    const size_t szW1  = (size_t)DD * DFF;
    const size_t szW2  = (size_t)DFF * DD;
    const size_t WBYTES = (szQKV + szWO + szW1 + szW2) * LL * 2 + 4096;
    bool big = (off + WBYTES) <= ws_size;

    bf16 *wqkvT = nullptr, *woT = nullptr, *w1T = nullptr, *w2T = nullptr, *rot = nullptr;
    if (big) {
        wqkvT = (bf16*)alloc(LL * szQKV * 2);
        woT   = (bf16*)alloc(LL * szWO * 2);
        w1T   = (bf16*)alloc(LL * szW1 * 2);
        w2T   = (bf16*)alloc(LL * szW2 * 2);
        transpose_w<<<dim3(3072 / 32, 1024 / 32, LL), 256, 0, stream>>>(Wqkv, wqkvT, 1024, 3072);
        transpose_w<<<dim3(1024 / 32, 1024 / 32, LL), 256, 0, stream>>>(Wo, woT, 1024, 1024);
        transpose_w<<<dim3(4096 / 32, 1024 / 32, LL), 256, 0, stream>>>(W1, w1T, 1024, 4096);
        transpose_w<<<dim3(1024 / 32, 4096 / 32, LL), 256, 0, stream>>>(W2, w2T, 4096, 1024);
    } else {
        rot = (bf16*)alloc(szW1 * 2);   // largest slice; stream order serializes reuse
    }
    w5_kernel<<<(OO * DD) / 256, 256, 0, stream>>>(Wout, w5T);

    // ---------------- context pass: 64 batches x 16 tokens ----------------
    stats_ctx_kernel<<<B2, 64, 0, stream>>>(x, ctx_mu, ctx_sg, ispos, normed);
    {
        const int R = B2 * NPATCH;   // 1024 rows
        embed_kernel<<<R, 256, 0, stream>>>(normed, W_in, b_in, hdd);
        for (int l = 0; l < LL; l++) {
            bf16* kc = kcache + l * cache_l;
            bf16* vc = vcache + l * cache_l;
            layernorm_kernel<<<R, 256, 0, stream>>>(hdd, xn, ln1_s + l * DD);
            bf16* bq;
            if (big) bq = wqkvT + l * szQKV;
            else { transpose_w<<<dim3(96, 32, 1), 256, 0, stream>>>(Wqkv + l * szQKV, rot, 1024, 3072); bq = rot; }
            hgemm<64, 128, 0><<<dim3(24, 16, 1), 256, 0, stream>>>(xn, bq, qkvb, nullptr, R, 3072, 1024, 1024);
            scatter_kv_kernel<<<(R * DD) / 256, 256, 0, stream>>>(qkvb, kc, vc, NPATCH, 0);
            attn_kernel<<<B2 * HH * NPATCH, 64, 0, stream>>>(qkvb, kc, vc, attnb, NPATCH, 0);
            bf16* bo;
            if (big) bo = woT + l * szWO;
            else { transpose_w<<<dim3(32, 32, 1), 256, 0, stream>>>(Wo + l * szWO, rot, 1024, 1024); bo = rot; }
            hgemm<64, 64, 2><<<dim3(16, 16, 2), 256, 0, stream>>>(attnb, bo, hdd, nullptr, R, 1024, 1024, 512);
            layernorm_kernel<<<R, 256, 0, stream>>>(hdd, xn, ln2_s + l * DD);
            bf16* b1;
            if (big) b1 = w1T + l * szW1;
            else { transpose_w<<<dim3(128, 32, 1), 256, 0, stream>>>(W1 + l * szW1, rot, 1024, 4096); b1 = rot; }
            hgemm<64, 128, 1><<<dim3(32, 16, 1), 256, 0, stream>>>(xn, b1, nullptr, ffnb, R, 4096, 1024, 1024);
            bf16* b2;
            if (big) b2 = w2T + l * szW2;
            else { transpose_w<<<dim3(32, 128, 1), 256, 0, stream>>>(W2 + l * szW2, rot, 4096, 1024); b2 = rot; }
            hgemm<64, 64, 2><<<dim3(16, 16, 4), 256, 0, stream>>>(ffnb, b2, hdd, nullptr, R, 1024, 4096, 1024);
        }
        layernorm_kernel<<<R, 256, 0, stream>>>(hdd, xn, lnf_s);
        out5_kernel<<<B2, 128, 0, stream>>>(xn, w5T, ctx_mu, ctx_sg, lastc, NPATCH);
    }

    // ---------------- AR pass: 64 batches x 4 tokens ----------------
    stats_ar_kernel<<<B2, 64, 0, stream>>>(lastc, ctx_mu, ctx_sg, nmu, nsg, normed);
    {
        const int R = B2 * MM;       // 256 rows
        const int QN = R * 3 * DD;   // qkvb elems to zero for split-K atomic
        embed_kernel<<<R, 256, 0, stream>>>(normed, W_in, b_in, hdd);
        for (int l = 0; l < LL; l++) {
            bf16* kc = kcache + l * cache_l;
            bf16* vc = vcache + l * cache_l;
            layernorm_kernel<<<R, 256, 0, stream>>>(hdd, xn, ln1_s + l * DD);
            bf16* bq;
            if (big) bq = wqkvT + l * szQKV;
            else { transpose_w<<<dim3(96, 32, 1), 256, 0, stream>>>(Wqkv + l * szQKV, rot, 1024, 3072); bq = rot; }
            zero_kernel<<<(QN + 255) / 256, 256, 0, stream>>>(qkvb, QN);
            hgemm<64, 64, 0><<<dim3(48, 4, 2), 256, 0, stream>>>(xn, bq, qkvb, nullptr, R, 3072, 1024, 512);
            scatter_kv_kernel<<<(R * DD) / 256, 256, 0, stream>>>(qkvb, kc, vc, MM, NPATCH);
            attn_kernel<<<B2 * HH * MM, 64, 0, stream>>>(qkvb, kc, vc, attnb, MM, NPATCH);
            bf16* bo;
            if (big) bo = woT + l * szWO;
            else { transpose_w<<<dim3(32, 32, 1), 256, 0, stream>>>(Wo + l * szWO, rot, 1024, 1024); bo = rot; }
            hgemm<64, 64, 2><<<dim3(16, 4, 4), 256, 0, stream>>>(attnb, bo, hdd, nullptr, R, 1024, 1024, 256);
            layernorm_kernel<<<R, 256, 0, stream>>>(hdd, xn, ln2_s + l * DD);
            bf16* b1;
            if (big) b1 = w1T + l * szW1;
            else { transpose_w<<<dim3(128, 32, 1), 256, 0, stream>>>(W1 + l * szW1, rot, 1024, 4096); b1 = rot; }
            hgemm<64, 64, 1><<<dim3(64, 4, 1), 256, 0, stream>>>(xn, b1, nullptr, ffnb, R, 4096, 1024, 1024);
            bf16* b2;
            if (big) b2 = w2T + l * szW2;
            else { transpose_w<<<dim3(32, 128, 1), 256, 0, stream>>>(W2 + l * szW2, rot, 4096, 1024); b2 = rot; }
            hgemm<64, 64, 2><<<dim3(16, 4, 8), 256, 0, stream>>>(ffnb, b2, hdd, nullptr, R, 1024, 4096, 512);
        }
        layernorm_kernel<<<R, 256, 0, stream>>>(hdd, xn, lnf_s);
        out5_kernel<<<B2, 128, 0, stream>>>(xn, w5T, nmu, nsg, lasta, MM);
    }

    // ---------------- combine +x / -x and emit ----------------
    combine_kernel<<<(32 * 256) / 256, 256, 0, stream>>>(lastc, lasta, ispos, out);
}